// Round 11
// baseline (79.533 us; speedup 1.0000x reference)
//
#include <hip/hip_runtime.h>

// out = f1>=0 ? f1*winMax9x9(f2pad) : f1*winMin9x9(f2pad)  (separable 9-window)
// REGISTER-ONLY: no LDS storage, no barriers. One wave = one 64-col strip
// (2 overlapping strips cover the 68 cols; lane = col, coalesced). Per 10-row
// band: 18 coalesced f2 loads -> vertical van Herk in registers -> horizontal
// sliding 9-window via lane shuffles (doubling: shfl 1,2,4 of partials +
// shfl 8 of original) -> sign-select multiply -> store (lanes 0..33).
// Shuffle wrap-garbage confined to lanes >=42; outputs read <= lane 41.

#define HH 38
#define WW 68
#define PLANE (HH * WW)   // 2584
#define TPB 256           // 4 waves = 2 planes (2 strips each)
#define NB 4096           // 8192 planes / 2 per block

template <int H0, int NR, int ILO, int IHI>
__device__ __forceinline__ void band(
    const int l, const int base, const int c, const bool cval,
    const int outc, const bool sok,
    const float* __restrict__ f1, const float* __restrict__ f2p,
    float* __restrict__ out)
{
    const int i1 = l + 1, i2 = l + 2, i4 = l + 4, i8 = l + 8;

    // ---- load NR+8 rows of this lane's column (zeros outside plane/col) ----
    float v[NR + 8];
    #pragma unroll
    for (int i = 0; i < NR + 8; ++i) {
        const bool ok = cval && (i >= ILO) && (i <= IHI);
        v[i] = ok ? f2p[(H0 - 4 + i) * WW + c] : 0.0f;
    }

    // ---- vertical van Herk: suffix over v[0..8] ----
    float Sx[9], Sn[9];
    Sx[8] = v[8]; Sn[8] = v[8];
    #pragma unroll
    for (int i = 7; i >= 0; --i) {
        Sx[i] = fmaxf(v[i], Sx[i + 1]);
        Sn[i] = fminf(v[i], Sn[i + 1]);
    }
    float Px = v[9], Pn = v[9];                    // prefix over v[9..]

    #pragma unroll
    for (int k = 0; k < NR; ++k) {
        // vertical 9-window for out row H0+k: window v[k..k+8]
        float vx, vn;
        if (k == 0)       { vx = Sx[0];            vn = Sn[0]; }
        else if (k <= 8)  { vx = fmaxf(Sx[k], Px); vn = fminf(Sn[k], Pn); }
        else              { vx = Px;               vn = Pn;    }  // k==9: v[9..17]
        if (k >= 1 && k <= 8) {                    // P_k = op(v[9..9+k]) for next iter
            Px = fmaxf(Px, v[9 + k]);
            Pn = fminf(Pn, v[9 + k]);
        }

        // horizontal sliding 9-window across lanes: w[l] = op(v[l..l+8])
        float m = fmaxf(vx, __shfl(vx, i1));
        m = fmaxf(m, __shfl(m, i2));
        m = fmaxf(m, __shfl(m, i4));               // window 8: lanes l..l+7
        const float wx = fmaxf(m, __shfl(vx, i8)); // + lane l+8
        float n = fminf(vn, __shfl(vn, i1));
        n = fminf(n, __shfl(n, i2));
        n = fminf(n, __shfl(n, i4));
        const float wn = fminf(n, __shfl(vn, i8));

        // combine with f1, store (lanes 0..33 -> 34 consecutive cols)
        if (sok) {
            const int idx = base + (H0 + k) * WW + outc;
            const float a = f1[idx];
            out[idx] = a * (a >= 0.0f ? wx : wn);
        }
    }
}

__global__ __launch_bounds__(TPB) void corr_shfl_kernel(
    const float* __restrict__ f1, const float* __restrict__ f2,
    float* __restrict__ out)
{
    const int t = threadIdx.x;
    const int w = t >> 6, l = t & 63;
    const int plane = blockIdx.x * 2 + (w >> 1);
    const int strip = w & 1;
    const int base  = plane * PLANE;
    const float* f2p = f2 + base;

    // strip 0: lane l holds col l-4 (cols -4..59); outputs cols 0..33
    // strip 1: lane l holds col l+30 (cols 30..93); outputs cols 34..67
    const int  c    = strip ? l + 30 : l - 4;
    const bool cval = strip ? (l <= 37) : (l >= 4);
    const int  outc = strip ? l + 34 : l;
    const bool sok  = (l < 34);

    band< 0, 10, 4, 17>(l, base, c, cval, outc, sok, f1, f2p, out); // rows  0..9
    band<10, 10, 0, 17>(l, base, c, cval, outc, sok, f1, f2p, out); // rows 10..19
    band<20, 10, 0, 17>(l, base, c, cval, outc, sok, f1, f2p, out); // rows 20..29
    band<30,  8, 0, 11>(l, base, c, cval, outc, sok, f1, f2p, out); // rows 30..37
}

extern "C" void kernel_launch(void* const* d_in, const int* in_sizes, int n_in,
                              void* d_out, int out_size, void* d_ws, size_t ws_size,
                              hipStream_t stream) {
    const float* f1 = (const float*)d_in[0];
    const float* f2 = (const float*)d_in[1];
    float* out = (float*)d_out;
    corr_shfl_kernel<<<dim3(NB), dim3(TPB), 0, stream>>>(f1, f2, out);
}